// Round 1
// baseline (594.179 us; speedup 1.0000x reference)
//
#include <hip/hip_runtime.h>
#include <hip/hip_bf16.h>
#include <stdint.h>

#define TOKENS 8192
#define IN_F   4096
#define OUT_F  4096

typedef __attribute__((ext_vector_type(4))) float f32x4;
typedef __attribute__((ext_vector_type(8))) short bf16x8;
typedef unsigned short u16;

// RNE fp32 -> bf16 (inputs are finite normals; int8 values convert exactly)
__device__ __forceinline__ u16 f2bf(float f) {
    uint32_t u = __builtin_bit_cast(uint32_t, f);
    u += 0x7fffu + ((u >> 16) & 1u);
    return (u16)(u >> 16);
}

// ---- x: fp32 -> bf16, 8 elems/thread ----
__global__ void __launch_bounds__(256) conv_x_kernel(const float4* __restrict__ in,
                                                     uint4* __restrict__ out, int n8) {
    int i = blockIdx.x * blockDim.x + threadIdx.x;
    const int stride = gridDim.x * blockDim.x;
    for (; i < n8; i += stride) {
        float4 a = in[2 * i], b = in[2 * i + 1];
        union { u16 u[8]; uint4 v; } r;
        r.u[0] = f2bf(a.x); r.u[1] = f2bf(a.y); r.u[2] = f2bf(a.z); r.u[3] = f2bf(a.w);
        r.u[4] = f2bf(b.x); r.u[5] = f2bf(b.y); r.u[6] = f2bf(b.z); r.u[7] = f2bf(b.w);
        out[i] = r.v;
    }
}

// ---- W: int (widened int8) -> bf16 (exact), 8 elems/thread ----
__global__ void __launch_bounds__(256) conv_w_kernel(const int4* __restrict__ in,
                                                     uint4* __restrict__ out, int n8) {
    int i = blockIdx.x * blockDim.x + threadIdx.x;
    const int stride = gridDim.x * blockDim.x;
    for (; i < n8; i += stride) {
        int4 a = in[2 * i], b = in[2 * i + 1];
        union { u16 u[8]; uint4 v; } r;
        r.u[0] = f2bf((float)a.x); r.u[1] = f2bf((float)a.y);
        r.u[2] = f2bf((float)a.z); r.u[3] = f2bf((float)a.w);
        r.u[4] = f2bf((float)b.x); r.u[5] = f2bf((float)b.y);
        r.u[6] = f2bf((float)b.z); r.u[7] = f2bf((float)b.w);
        out[i] = r.v;
    }
}

// ---- bf16 B^T GEMM, 128x128 tile, BK=32, 4 waves, global_load_lds(16B) ----
#define BM 128
#define BN 128
#define BK 32

#define GLOAD_LDS16(g, l) __builtin_amdgcn_global_load_lds( \
    (const __attribute__((address_space(1))) void*)(g),     \
    (__attribute__((address_space(3))) void*)(l), 16, 0, 0)

__global__ void __launch_bounds__(256) gemm_kernel(
    const u16* __restrict__ A,      // [TOKENS][IN_F] bf16 bits
    const u16* __restrict__ B,      // [OUT_F][IN_F]  bf16 bits (exact int8)
    const float* __restrict__ scales,  // [OUT_F]
    const float* __restrict__ bias,    // [OUT_F]
    float* __restrict__ C)             // [TOKENS][OUT_F]
{
    __shared__ u16 sA[BM * BK];   // 8 KB, linear [row][k]
    __shared__ u16 sB[BN * BK];   // 8 KB

    const int nbn = OUT_F / BN;                 // 32
    const int nwg = (TOKENS / BM) * nbn;        // 2048 (divisible by 8)
    const int bid = blockIdx.x;
    const int wg  = (bid & 7) * (nwg >> 3) + (bid >> 3);  // XCD-aware swizzle
    const int m0  = (wg / nbn) * BM;
    const int n0  = (wg % nbn) * BN;

    const int t    = threadIdx.x;
    const int lane = t & 63;
    const int wid  = t >> 6;        // 0..3
    const int wr   = wid >> 1;      // wave row 0..1 (64 rows each)
    const int wc   = wid & 1;       // wave col 0..1

    f32x4 acc[4][4] = {};

    // staging: 512 chunks of 16B per tile; thread t covers chunk t (issue 0)
    // and t+256 (issue 1). chunk c -> row c>>2, k-offset (c&3)*8.
    const int rowS  = t >> 2;
    const int ksegS = (t & 3) * 8;
    const u16* gA0 = A + (size_t)(m0 + rowS) * IN_F + ksegS;
    const u16* gA1 = A + (size_t)(m0 + 64 + rowS) * IN_F + ksegS;
    const u16* gB0 = B + (size_t)(n0 + rowS) * IN_F + ksegS;
    const u16* gB1 = B + (size_t)(n0 + 64 + rowS) * IN_F + ksegS;
    // wave-uniform LDS bases (lane*16B is appended by HW)
    u16* lA0 = &sA[(wid * 64) * 8];
    u16* lA1 = &sA[(256 + wid * 64) * 8];
    u16* lB0 = &sB[(wid * 64) * 8];
    u16* lB1 = &sB[(256 + wid * 64) * 8];

    // fragment read indices: lane l reads row (base + l&15), 8 k at (l>>4)*8
    const int ra   = wr * 64 + (lane & 15);
    const int rb   = wc * 64 + (lane & 15);
    const int koff = lane >> 4;
    const bf16x8* fA = reinterpret_cast<const bf16x8*>(sA);
    const bf16x8* fB = reinterpret_cast<const bf16x8*>(sB);

    for (int k0 = 0; k0 < IN_F; k0 += BK) {
        __syncthreads();                 // previous compute done; LDS reusable
        GLOAD_LDS16(gA0 + k0, lA0);
        GLOAD_LDS16(gA1 + k0, lA1);
        GLOAD_LDS16(gB0 + k0, lB0);
        GLOAD_LDS16(gB1 + k0, lB1);
        __syncthreads();                 // drains vmcnt before barrier

        bf16x8 af[4], bfr[4];
#pragma unroll
        for (int mi = 0; mi < 4; ++mi) af[mi]  = fA[(ra + mi * 16) * 4 + koff];
#pragma unroll
        for (int ni = 0; ni < 4; ++ni) bfr[ni] = fB[(rb + ni * 16) * 4 + koff];
#pragma unroll
        for (int mi = 0; mi < 4; ++mi)
#pragma unroll
            for (int ni = 0; ni < 4; ++ni)
                acc[mi][ni] = __builtin_amdgcn_mfma_f32_16x16x32_bf16(
                    af[mi], bfr[ni], acc[mi][ni], 0, 0, 0);
    }

    // epilogue: C/D layout col = lane&15, row = (lane>>4)*4 + j  [m89-verified]
    const int crow0 = (lane >> 4) * 4;
    const int ccol  = lane & 15;
#pragma unroll
    for (int ni = 0; ni < 4; ++ni) {
        const int col = n0 + wc * 64 + ni * 16 + ccol;
        const float s  = scales[col];
        const float bv = bias[col];
#pragma unroll
        for (int mi = 0; mi < 4; ++mi) {
            const int rbase = m0 + wr * 64 + mi * 16 + crow0;
#pragma unroll
            for (int j = 0; j < 4; ++j) {
                C[(size_t)(rbase + j) * OUT_F + col] = acc[mi][ni][j] * s + bv;
            }
        }
    }
}

extern "C" void kernel_launch(void* const* d_in, const int* in_sizes, int n_in,
                              void* d_out, int out_size, void* d_ws, size_t ws_size,
                              hipStream_t stream) {
    const float* x      = (const float*)d_in[0];
    const int*   w8     = (const int*)d_in[1];     // harness widens ints -> int32
    const float* scales = (const float*)d_in[2];
    const float* bias   = (const float*)d_in[3];
    float*       out    = (float*)d_out;

    u16* xbf = (u16*)d_ws;                                          // 64 MiB
    u16* wbf = (u16*)((char*)d_ws + (size_t)TOKENS * IN_F * 2);     // +32 MiB

    conv_x_kernel<<<2048, 256, 0, stream>>>((const float4*)x, (uint4*)xbf,
                                            TOKENS * IN_F / 8);
    conv_w_kernel<<<2048, 256, 0, stream>>>((const int4*)w8, (uint4*)wbf,
                                            OUT_F * IN_F / 8);
    gemm_kernel<<<2048, 256, 0, stream>>>(xbf, wbf, scales, bias, out);
}

// Round 2
// 516.839 us; speedup vs baseline: 1.1496x; 1.1496x over previous
//
#include <hip/hip_runtime.h>
#include <hip/hip_bf16.h>
#include <stdint.h>

#define TOKENS 8192
#define IN_F   4096
#define OUT_F  4096
#define NT     (IN_F / 64)          // 64 K-tiles of BK=64

typedef __attribute__((ext_vector_type(4))) float f32x4;
typedef __attribute__((ext_vector_type(8))) short bf16x8;
typedef unsigned short u16;

// RNE fp32 -> bf16
__device__ __forceinline__ u16 f2bf(float f) {
    uint32_t u = __builtin_bit_cast(uint32_t, f);
    u += 0x7fffu + ((u >> 16) & 1u);
    return (u16)(u >> 16);
}

__global__ void __launch_bounds__(256) conv_x_kernel(const float4* __restrict__ in,
                                                     uint4* __restrict__ out, int n8) {
    int i = blockIdx.x * blockDim.x + threadIdx.x;
    const int stride = gridDim.x * blockDim.x;
    for (; i < n8; i += stride) {
        float4 a = in[2 * i], b = in[2 * i + 1];
        union { u16 u[8]; uint4 v; } r;
        r.u[0] = f2bf(a.x); r.u[1] = f2bf(a.y); r.u[2] = f2bf(a.z); r.u[3] = f2bf(a.w);
        r.u[4] = f2bf(b.x); r.u[5] = f2bf(b.y); r.u[6] = f2bf(b.z); r.u[7] = f2bf(b.w);
        out[i] = r.v;
    }
}

__global__ void __launch_bounds__(256) conv_w_kernel(const int4* __restrict__ in,
                                                     uint4* __restrict__ out, int n8) {
    int i = blockIdx.x * blockDim.x + threadIdx.x;
    const int stride = gridDim.x * blockDim.x;
    for (; i < n8; i += stride) {
        int4 a = in[2 * i], b = in[2 * i + 1];
        union { u16 u[8]; uint4 v; } r;
        r.u[0] = f2bf((float)a.x); r.u[1] = f2bf((float)a.y);
        r.u[2] = f2bf((float)a.z); r.u[3] = f2bf((float)a.w);
        r.u[4] = f2bf((float)b.x); r.u[5] = f2bf((float)b.y);
        r.u[6] = f2bf((float)b.z); r.u[7] = f2bf((float)b.w);
        out[i] = r.v;
    }
}

// ============================ 256x256 8-phase GEMM ============================
// LDS: 8 half-tile slots x 16KB = 128KB. slot(mat,half,par) = mat*4+half*2+par.
// K-tile t uses parity t&1. Stage conveyor: P1:Ah1(t+1) P2:Bh0(t+2) P3:Bh1(t+2)
// P4:Ah0(t+2); vmcnt(6) once per tile at P4 (3 half-tiles in flight).

#define GLOAD_LDS16(g, l) __builtin_amdgcn_global_load_lds( \
    (const __attribute__((address_space(1))) void*)(g),     \
    (__attribute__((address_space(3))) void*)(l), 16, 0, 0)

#define SLOT_BYTES 16384

// one MFMA quadrant: 4 m-frags x 2 n-frags x 2 k-steps = 16 MFMA
#define PHASE_MMA(QM, QN)                                                      \
    do {                                                                       \
        __builtin_amdgcn_s_setprio(1);                                         \
        _Pragma("unroll")                                                      \
        for (int i = 0; i < 4; ++i) {                                          \
            _Pragma("unroll")                                                  \
            for (int j = 0; j < 2; ++j) {                                      \
                acc[(QM)*4 + i][(QN)*2 + j] =                                  \
                    __builtin_amdgcn_mfma_f32_16x16x32_bf16(                   \
                        a[i][0], b[(QN)*2 + j][0], acc[(QM)*4 + i][(QN)*2 + j], 0, 0, 0); \
                acc[(QM)*4 + i][(QN)*2 + j] =                                  \
                    __builtin_amdgcn_mfma_f32_16x16x32_bf16(                   \
                        a[i][1], b[(QN)*2 + j][1], acc[(QM)*4 + i][(QN)*2 + j], 0, 0, 0); \
            }                                                                  \
        }                                                                      \
        __builtin_amdgcn_s_setprio(0);                                         \
    } while (0)

__global__ void __launch_bounds__(512, 2) gemm8_kernel(
    const u16* __restrict__ A,        // [TOKENS][IN_F] bf16
    const u16* __restrict__ B,        // [OUT_F][IN_F]  bf16 (exact int8)
    const float* __restrict__ scales,
    const float* __restrict__ bias,
    float* __restrict__ C)
{
    extern __shared__ char smem[];

    const int t   = threadIdx.x;
    const int lane = t & 63;
    const int w    = t >> 6;          // 0..7
    const int wm   = w >> 2;          // 0..1 (M)
    const int wn   = w & 3;           // 0..3 (N)
    const int hn   = wn >> 1;         // B half this wave reads

    const int nbn = OUT_F / 256;                  // 16
    const int nwg = (TOKENS / 256) * nbn;         // 512 (divisible by 8)
    const int bid = blockIdx.x;
    const int wg  = (bid & 7) * (nwg >> 3) + (bid >> 3);
    const int m0  = (wg / nbn) * 256;
    const int n0  = (wg % nbn) * 256;

    // ---- staging per-lane constants (st_16x32 swizzle pre-applied to SOURCE) ----
    const int rowLane = w * 8 + (lane >> 3);                       // 0..63
    const int ksegOff = ((lane & 7) ^ (((lane >> 5) & 1) << 1)) * 8;
    char* const ldsW  = smem + w * 1024;                           // wave-uniform

    // ---- fragment-read per-lane constants (swizzle applied to READ addr) ----
    const int laneRow = lane & 15;
    const int kb0 = ((lane >> 4) * 16) ^ ((lane & 4) << 3);        // ks=0 byte
    const int kb1 = kb0 + 64;                                      // ks=1 byte

    f32x4 acc[8][4] = {};
    bf16x8 a[4][2], b[4][2];

    auto STAGE = [&](const u16* mat, int rowBase, int half, int tt, int slotIdx) {
        const u16* s0 = mat + (size_t)(rowBase + half * 128 + rowLane) * IN_F
                            + tt * 64 + ksegOff;
        char* dst = ldsW + slotIdx * SLOT_BYTES;
        GLOAD_LDS16(s0, dst);
        GLOAD_LDS16(s0 + (size_t)64 * IN_F, dst + 8192);
    };
    auto RDA = [&](const char* aS, int qm) {
#pragma unroll
        for (int mi = 0; mi < 4; ++mi) {
            const int rb = (qm * 64 + mi * 16 + laneRow) * 128;
            a[mi][0] = *(const bf16x8*)(aS + rb + kb0);
            a[mi][1] = *(const bf16x8*)(aS + rb + kb1);
        }
    };
    auto RDB = [&](const char* bS) {
#pragma unroll
        for (int ni = 0; ni < 4; ++ni) {
            const int rb = ((wn & 1) * 64 + ni * 16 + laneRow) * 128;
            b[ni][0] = *(const bf16x8*)(bS + rb + kb0);
            b[ni][1] = *(const bf16x8*)(bS + rb + kb1);
        }
    };

    // ---- prologue: tile0 (parity 0) fully + tile1 (parity 1) minus Ah1 ----
    STAGE(B, n0, 0, 0, 1*4 + 0*2 + 0);   // Bh0(0)
    STAGE(B, n0, 1, 0, 1*4 + 1*2 + 0);   // Bh1(0)
    STAGE(A, m0, 0, 0, 0*4 + 0*2 + 0);   // Ah0(0)
    STAGE(A, m0, 1, 0, 0*4 + 1*2 + 0);   // Ah1(0)
    STAGE(B, n0, 0, 1, 1*4 + 0*2 + 1);   // Bh0(1)
    STAGE(B, n0, 1, 1, 1*4 + 1*2 + 1);   // Bh1(1)
    STAGE(A, m0, 0, 1, 0*4 + 0*2 + 1);   // Ah0(1)
    asm volatile("s_waitcnt vmcnt(6)" ::: "memory");   // tile0 complete
    __builtin_amdgcn_sched_barrier(0);
    __builtin_amdgcn_s_barrier();

    for (int kt = 0; kt < NT; ++kt) {
        const int p  = kt & 1, np = p ^ 1;
        const char* aS = smem + (0*4 + wm * 2 + p) * SLOT_BYTES;
        const char* bS = smem + (1*4 + hn * 2 + p) * SLOT_BYTES;
        const int t1 = (kt + 1 < NT) ? kt + 1 : NT - 1;
        const int t2 = (kt + 2 < NT) ? kt + 2 : NT - 1;

        // ---- P1: reads A(qm0)+all B; stage Ah1(t+1); MFMA (0,0) ----
        RDA(aS, 0);
        RDB(bS);
        STAGE(A, m0, 1, t1, 0*4 + 1*2 + np);
        __builtin_amdgcn_s_barrier();
        PHASE_MMA(0, 0);
        asm volatile("s_waitcnt lgkmcnt(0)" ::: "memory");  // all reads done pre-barrier
        __builtin_amdgcn_sched_barrier(0);
        __builtin_amdgcn_s_barrier();

        // ---- P2: stage Bh0(t+2); MFMA (0,1) ----
        STAGE(B, n0, 0, t2, 1*4 + 0*2 + p);
        __builtin_amdgcn_s_barrier();
        PHASE_MMA(0, 1);
        __builtin_amdgcn_s_barrier();

        // ---- P3: reads A(qm1); stage Bh1(t+2); MFMA (1,0) ----
        RDA(aS, 1);
        STAGE(B, n0, 1, t2, 1*4 + 1*2 + p);
        __builtin_amdgcn_s_barrier();
        PHASE_MMA(1, 0);
        asm volatile("s_waitcnt lgkmcnt(0)" ::: "memory");
        __builtin_amdgcn_sched_barrier(0);
        __builtin_amdgcn_s_barrier();

        // ---- P4: stage Ah0(t+2); MFMA (1,1); counted vmcnt ----
        STAGE(A, m0, 0, t2, 0*4 + 0*2 + p);
        __builtin_amdgcn_s_barrier();
        PHASE_MMA(1, 1);
        asm volatile("s_waitcnt vmcnt(6)" ::: "memory");    // tile t+1 ready; 3 HT in flight
        __builtin_amdgcn_sched_barrier(0);
        __builtin_amdgcn_s_barrier();
    }

    // ---- epilogue: scale+bias, fp32 store ----
    const int crow = (lane >> 4) * 4;
    const int ccol = lane & 15;
#pragma unroll
    for (int ni = 0; ni < 4; ++ni) {
        const int col = n0 + wn * 64 + ni * 16 + ccol;
        const float s  = scales[col];
        const float bv = bias[col];
#pragma unroll
        for (int mi = 0; mi < 8; ++mi) {
            const int rbase = m0 + wm * 128 + mi * 16 + crow;
#pragma unroll
            for (int j = 0; j < 4; ++j)
                C[(size_t)(rbase + j) * OUT_F + col] = acc[mi][ni][j] * s + bv;
        }
    }
}

extern "C" void kernel_launch(void* const* d_in, const int* in_sizes, int n_in,
                              void* d_out, int out_size, void* d_ws, size_t ws_size,
                              hipStream_t stream) {
    const float* x      = (const float*)d_in[0];
    const int*   w8     = (const int*)d_in[1];
    const float* scales = (const float*)d_in[2];
    const float* bias   = (const float*)d_in[3];
    float*       out    = (float*)d_out;

    u16* xbf = (u16*)d_ws;
    u16* wbf = (u16*)((char*)d_ws + (size_t)TOKENS * IN_F * 2);

    conv_x_kernel<<<2048, 256, 0, stream>>>((const float4*)x, (uint4*)xbf,
                                            TOKENS * IN_F / 8);
    conv_w_kernel<<<2048, 256, 0, stream>>>((const int4*)w8, (uint4*)wbf,
                                            OUT_F * IN_F / 8);

    static bool attr_set = []() {
        hipFuncSetAttribute(reinterpret_cast<const void*>(gemm8_kernel),
                            hipFuncAttributeMaxDynamicSharedMemorySize, 131072);
        return true;
    }();
    (void)attr_set;

    gemm8_kernel<<<512, 512, 131072, stream>>>(xbf, wbf, scales, bias, out);
}

// Round 4
// 501.087 us; speedup vs baseline: 1.1858x; 1.0314x over previous
//
#include <hip/hip_runtime.h>
#include <hip/hip_bf16.h>
#include <stdint.h>

#define TOKENS 8192
#define IN_F   4096
#define OUT_F  4096
#define NT     (IN_F / 64)          // 64 K-tiles of BK=64

typedef __attribute__((ext_vector_type(4))) float f32x4;
typedef __attribute__((ext_vector_type(8))) short bf16x8;
typedef unsigned short u16;

// RNE fp32 -> bf16
__device__ __forceinline__ u16 f2bf(float f) {
    uint32_t u = __builtin_bit_cast(uint32_t, f);
    u += 0x7fffu + ((u >> 16) & 1u);
    return (u16)(u >> 16);
}

__global__ void __launch_bounds__(256) conv_x_kernel(const float4* __restrict__ in,
                                                     uint4* __restrict__ out, int n8) {
    int i = blockIdx.x * blockDim.x + threadIdx.x;
    const int stride = gridDim.x * blockDim.x;
    for (; i < n8; i += stride) {
        float4 a = in[2 * i], b = in[2 * i + 1];
        union { u16 u[8]; uint4 v; } r;
        r.u[0] = f2bf(a.x); r.u[1] = f2bf(a.y); r.u[2] = f2bf(a.z); r.u[3] = f2bf(a.w);
        r.u[4] = f2bf(b.x); r.u[5] = f2bf(b.y); r.u[6] = f2bf(b.z); r.u[7] = f2bf(b.w);
        out[i] = r.v;
    }
}

__global__ void __launch_bounds__(256) conv_w_kernel(const int4* __restrict__ in,
                                                     uint4* __restrict__ out, int n8) {
    int i = blockIdx.x * blockDim.x + threadIdx.x;
    const int stride = gridDim.x * blockDim.x;
    for (; i < n8; i += stride) {
        int4 a = in[2 * i], b = in[2 * i + 1];
        union { u16 u[8]; uint4 v; } r;
        r.u[0] = f2bf((float)a.x); r.u[1] = f2bf((float)a.y);
        r.u[2] = f2bf((float)a.z); r.u[3] = f2bf((float)a.w);
        r.u[4] = f2bf((float)b.x); r.u[5] = f2bf((float)b.y);
        r.u[6] = f2bf((float)b.z); r.u[7] = f2bf((float)b.w);
        out[i] = r.v;
    }
}

// ============================ 256x256 8-phase GEMM ============================
// LDS: 8 half-tile slots x 16KB = 128KB. slot(mat,half,par) = mat*4+half*2+par.
// K-tile t uses parity t&1. Stage conveyor: P1:Ah1(t+1) P2:Bh0(t+2) P3:Bh1(t+2)
// P4:Ah0(t+2); vmcnt(6) once per tile at P4 (3 half-tiles in flight).
// Swizzle (both sides): 16B-chunk index ^= (row & 7)   [full 3-bit st_16x32]

#define GLOAD_LDS16(g, l) __builtin_amdgcn_global_load_lds( \
    (const __attribute__((address_space(1))) void*)(g),     \
    (__attribute__((address_space(3))) void*)(l), 16, 0, 0)

#define SLOT_BYTES 16384

// one MFMA quadrant: 4 m-frags x 2 n-frags x 2 k-steps = 16 MFMA
#define PHASE_MMA(QM, QN)                                                      \
    do {                                                                       \
        __builtin_amdgcn_s_setprio(1);                                         \
        _Pragma("unroll")                                                      \
        for (int i = 0; i < 4; ++i) {                                          \
            _Pragma("unroll")                                                  \
            for (int j = 0; j < 2; ++j) {                                      \
                acc[(QM)*4 + i][(QN)*2 + j] =                                  \
                    __builtin_amdgcn_mfma_f32_16x16x32_bf16(                   \
                        a[i][0], b[(QN)*2 + j][0], acc[(QM)*4 + i][(QN)*2 + j], 0, 0, 0); \
                acc[(QM)*4 + i][(QN)*2 + j] =                                  \
                    __builtin_amdgcn_mfma_f32_16x16x32_bf16(                   \
                        a[i][1], b[(QN)*2 + j][1], acc[(QM)*4 + i][(QN)*2 + j], 0, 0, 0); \
            }                                                                  \
        }                                                                      \
        __builtin_amdgcn_s_setprio(0);                                         \
    } while (0)

__global__ void __launch_bounds__(512, 2) gemm8_kernel(
    const u16* __restrict__ A,        // [TOKENS][IN_F] bf16
    const u16* __restrict__ B,        // [OUT_F][IN_F]  bf16 (exact int8)
    const float* __restrict__ scales,
    const float* __restrict__ bias,
    float* __restrict__ C)
{
    extern __shared__ char smem[];

    const int t   = threadIdx.x;
    const int lane = t & 63;
    const int w    = t >> 6;          // 0..7
    const int wm   = w >> 2;          // 0..1 (M)
    const int wn   = w & 3;           // 0..3 (N)
    const int hn   = wn >> 1;         // B half this wave reads

    const int nbn = OUT_F / 256;                  // 16
    const int nwg = (TOKENS / 256) * nbn;         // 512 (divisible by 8)
    const int bid = blockIdx.x;
    const int wg  = (bid & 7) * (nwg >> 3) + (bid >> 3);
    const int m0  = (wg / nbn) * 256;
    const int n0  = (wg % nbn) * 256;

    // ---- staging per-lane constants (swizzle pre-applied to SOURCE) ----
    // lane l fills LDS row w*8+(l>>3), chunk (l&7); LDS[row][c] must hold
    // global chunk c ^ (row&7)  ->  source chunk = (l&7) ^ (l>>3)
    const int rowLane = w * 8 + (lane >> 3);                       // 0..63
    const int ksegOff = ((lane & 7) ^ (lane >> 3)) * 8;            // elements
    char* const ldsW  = smem + w * 1024;                           // wave-uniform

    // ---- fragment-read per-lane constants (swizzle applied to READ addr) ----
    const int laneRow = lane & 15;
    const int kb0 = ((lane >> 4) ^ (laneRow & 7)) << 4;            // ks=0 byte
    const int kb1 = kb0 ^ 64;                                      // ks=1 byte

    f32x4 acc[8][4] = {};
    bf16x8 a[4][2], b[4][2];

    auto STAGE = [&](const u16* mat, int rowBase, int half, int tt, int slotIdx) {
        const u16* s0 = mat + (size_t)(rowBase + half * 128 + rowLane) * IN_F
                            + tt * 64 + ksegOff;
        char* dst = ldsW + slotIdx * SLOT_BYTES;
        GLOAD_LDS16(s0, dst);
        GLOAD_LDS16(s0 + (size_t)64 * IN_F, dst + 8192);
    };
    auto RDA = [&](const char* aS, int qm) {
#pragma unroll
        for (int mi = 0; mi < 4; ++mi) {
            const int rb = (qm * 64 + mi * 16 + laneRow) * 128;
            a[mi][0] = *(const bf16x8*)(aS + rb + kb0);
            a[mi][1] = *(const bf16x8*)(aS + rb + kb1);
        }
    };
    auto RDB = [&](const char* bS) {
#pragma unroll
        for (int ni = 0; ni < 4; ++ni) {
            const int rb = ((wn & 1) * 64 + ni * 16 + laneRow) * 128;
            b[ni][0] = *(const bf16x8*)(bS + rb + kb0);
            b[ni][1] = *(const bf16x8*)(bS + rb + kb1);
        }
    };

    // ---- prologue: tile0 (parity 0) fully + tile1 (parity 1) minus Ah1 ----
    STAGE(B, n0, 0, 0, 1*4 + 0*2 + 0);   // Bh0(0)
    STAGE(B, n0, 1, 0, 1*4 + 1*2 + 0);   // Bh1(0)
    STAGE(A, m0, 0, 0, 0*4 + 0*2 + 0);   // Ah0(0)
    STAGE(A, m0, 1, 0, 0*4 + 1*2 + 0);   // Ah1(0)
    STAGE(B, n0, 0, 1, 1*4 + 0*2 + 1);   // Bh0(1)
    STAGE(B, n0, 1, 1, 1*4 + 1*2 + 1);   // Bh1(1)
    STAGE(A, m0, 0, 1, 0*4 + 0*2 + 1);   // Ah0(1)
    asm volatile("s_waitcnt vmcnt(6)" ::: "memory");   // tile0 complete
    __builtin_amdgcn_sched_barrier(0);
    __builtin_amdgcn_s_barrier();

    for (int kt = 0; kt < NT; ++kt) {
        const int p  = kt & 1, np = p ^ 1;
        const char* aS = smem + (0*4 + wm * 2 + p) * SLOT_BYTES;
        const char* bS = smem + (1*4 + hn * 2 + p) * SLOT_BYTES;
        const int t1 = (kt + 1 < NT) ? kt + 1 : NT - 1;
        const int t2 = (kt + 2 < NT) ? kt + 2 : NT - 1;

        // ---- P1: reads A(qm0)+all B; stage Ah1(t+1); MFMA (0,0) ----
        RDA(aS, 0);
        RDB(bS);
        STAGE(A, m0, 1, t1, 0*4 + 1*2 + np);
        __builtin_amdgcn_s_barrier();
        PHASE_MMA(0, 0);
        asm volatile("s_waitcnt lgkmcnt(0)" ::: "memory");  // all reads done pre-barrier
        __builtin_amdgcn_sched_barrier(0);
        __builtin_amdgcn_s_barrier();

        // ---- P2: stage Bh0(t+2); MFMA (0,1) ----
        STAGE(B, n0, 0, t2, 1*4 + 0*2 + p);
        __builtin_amdgcn_s_barrier();
        PHASE_MMA(0, 1);
        __builtin_amdgcn_s_barrier();

        // ---- P3: reads A(qm1); stage Bh1(t+2); MFMA (1,0) ----
        RDA(aS, 1);
        STAGE(B, n0, 1, t2, 1*4 + 1*2 + p);
        __builtin_amdgcn_s_barrier();
        PHASE_MMA(1, 0);
        asm volatile("s_waitcnt lgkmcnt(0)" ::: "memory");
        __builtin_amdgcn_sched_barrier(0);
        __builtin_amdgcn_s_barrier();

        // ---- P4: stage Ah0(t+2); MFMA (1,1); counted vmcnt ----
        STAGE(A, m0, 0, t2, 0*4 + 0*2 + p);
        __builtin_amdgcn_s_barrier();
        PHASE_MMA(1, 1);
        asm volatile("s_waitcnt vmcnt(6)" ::: "memory");    // tile t+1 ready; 3 HT in flight
        __builtin_amdgcn_sched_barrier(0);
        __builtin_amdgcn_s_barrier();
    }

    // ---- epilogue: scale+bias, fp32 store ----
    const int crow = (lane >> 4) * 4;
    const int ccol = lane & 15;
#pragma unroll
    for (int ni = 0; ni < 4; ++ni) {
        const int col = n0 + wn * 64 + ni * 16 + ccol;
        const float s  = scales[col];
        const float bv = bias[col];
#pragma unroll
        for (int mi = 0; mi < 8; ++mi) {
            const int rbase = m0 + wm * 128 + mi * 16 + crow;
#pragma unroll
            for (int j = 0; j < 4; ++j)
                C[(size_t)(rbase + j) * OUT_F + col] = acc[mi][ni][j] * s + bv;
        }
    }
}

extern "C" void kernel_launch(void* const* d_in, const int* in_sizes, int n_in,
                              void* d_out, int out_size, void* d_ws, size_t ws_size,
                              hipStream_t stream) {
    const float* x      = (const float*)d_in[0];
    const int*   w8     = (const int*)d_in[1];
    const float* scales = (const float*)d_in[2];
    const float* bias   = (const float*)d_in[3];
    float*       out    = (float*)d_out;

    u16* xbf = (u16*)d_ws;
    u16* wbf = (u16*)((char*)d_ws + (size_t)TOKENS * IN_F * 2);

    conv_x_kernel<<<2048, 256, 0, stream>>>((const float4*)x, (uint4*)xbf,
                                            TOKENS * IN_F / 8);
    conv_w_kernel<<<2048, 256, 0, stream>>>((const int4*)w8, (uint4*)wbf,
                                            OUT_F * IN_F / 8);

    static bool attr_set = []() {
        hipFuncSetAttribute(reinterpret_cast<const void*>(gemm8_kernel),
                            hipFuncAttributeMaxDynamicSharedMemorySize, 131072);
        return true;
    }();
    (void)attr_set;

    gemm8_kernel<<<512, 512, 131072, stream>>>(xbf, wbf, scales, bias, out);
}